// Round 2
// baseline (1684.626 us; speedup 1.0000x reference)
//
#include <hip/hip_runtime.h>
#include <cstddef>

// Bit-exact OpenBLAS-skylakex (KC=320) fp32 SNN — r8: two-kernel split-K.
// Chain order (verified r3/r4/r5): per (row,j) k ascending, panel folds at
// k=320/640 realized as 3 INDEPENDENT panel GEMMs (P1,P2,P3) combined as
// ((P1+P2)+P3)+b1 — identical association, bit-exact by construction.
// LIF literal order; layer2 cur2=mm+b2 then m2*0.25+cur2, j ascending.
//
// r8 design (from r7 post-mortem):
//  - r7 proved occupancy was grid-capped; fix it WITHOUT shrinking the 4x8
//    tile (LDS bytes/FMA is the GEMM floor) via split-K over the 3 panels:
//    K1 grid = 3*512 = 1536 blocks = 6 blocks/CU = 24 waves/CU.
//  - r7's WRITE_SIZE blew up 373->900 MB (NT 16B-at-32B-stride stopped
//    merging). K2 rebuilds spikes from the LDS bit-masks and stores them
//    in a DENSE pass: every wave-instruction writes a contiguous 1 KB.
//  - Partials live in rec[17..19] of `out` (50.3 MB scratch, no d_ws
//    dependency); each K2 block reads only its own rows before its st-loop
//    overwrites them (cur is register-resident from the start).

typedef float f32x4 __attribute__((ext_vector_type(4)));

constexpr int KDIM   = 784;
constexpr int NJ     = 128;
constexpr int NO     = 10;
constexpr int TSTEPS = 20;

// ---------------- K1: panel GEMM (rows 64, 256 thr, 4x8 tile, BK=8) -------
constexpr int BR1 = 64;
constexpr int BK1 = 8;     // 320 = 40*8, 144 = 18*8

__global__ __launch_bounds__(256, 6) void snn_gemm(
    const float* __restrict__ x,
    const float* __restrict__ W1,
    float* __restrict__ out,
    int B)
{
    __shared__ alignas(16) float xs[2][BK1][68];    // [buf][kk][row(64)+pad]
    __shared__ alignas(16) float ws[2][BK1][192];   // [buf][kk][16 chunks*12]

    const int bid  = blockIdx.x;
    const int p    = bid % 3;                       // panel: siblings adjacent
    const int rb   = bid / 3;
    const int kbeg = p * 320;
    const int nt   = (p < 2) ? 40 : 18;             // 320/8, 144/8
    const int t    = threadIdx.x;
    const int tx   = t & 15;                        // j = tx*8+jj
    const int ty   = t >> 4;                        // row = ty*4+rr
    const int r0   = rb * BR1;

    float acc[4][8];
    #pragma unroll
    for (int rr = 0; rr < 4; ++rr)
        #pragma unroll
        for (int jj = 0; jj < 8; ++jj) acc[rr][jj] = 0.0f;

    const int xrow = t >> 2, xkf = (t & 3) * 2;     // x: row(0..63), 2-k chunk
    const int wj   = t, wjr = t >> 1, wkf = (t & 1) * 4; // W1: j=t>>1, 4-k chunk
    const int wco  = wjr >> 3, wci = wjr & 7;
    const float* xrp = x  + (size_t)(r0 + xrow) * KDIM + kbeg + xkf;
    const float* wrp = W1 + (size_t)wjr * KDIM + kbeg + wkf;
    (void)wj;

    // preload tile 0 -> regs -> buf 0
    float2 xv = *(const float2*)(xrp);
    float4 wa = *(const float4*)(wrp);
    {
        xs[0][xkf][xrow] = xv.x; xs[0][xkf + 1][xrow] = xv.y;
        float* wp0 = &ws[0][wkf][wco * 12 + wci];   // k rows stride 192
        wp0[0] = wa.x; wp0[192] = wa.y; wp0[384] = wa.z; wp0[576] = wa.w;
    }
    __syncthreads();

    #pragma unroll 1
    for (int tt = 0; tt < nt; ++tt) {
        const int cb = tt & 1;
        if (tt < nt - 1) {                          // prefetch next tile
            const int k0n = (tt + 1) * BK1;
            xv = *(const float2*)(xrp + k0n);
            wa = *(const float4*)(wrp + k0n);
        }
        #pragma unroll
        for (int kk = 0; kk < BK1; ++kk) {          // strict ascending k
            float4 xr  = *(const float4*)&xs[cb][kk][ty * 4];
            float4 wva = *(const float4*)&ws[cb][kk][tx * 12];
            float4 wvb = *(const float4*)&ws[cb][kk][tx * 12 + 4];
            float xf[4] = {xr.x, xr.y, xr.z, xr.w};
            float wf[8] = {wva.x, wva.y, wva.z, wva.w, wvb.x, wvb.y, wvb.z, wvb.w};
            #pragma unroll
            for (int rr = 0; rr < 4; ++rr)
                #pragma unroll
                for (int jj = 0; jj < 8; ++jj)
                    acc[rr][jj] = fmaf(xf[rr], wf[jj], acc[rr][jj]);
        }
        if (tt < nt - 1) {
            const int nb = cb ^ 1;
            xs[nb][xkf][xrow] = xv.x; xs[nb][xkf + 1][xrow] = xv.y;
            float* wp0 = &ws[nb][wkf][wco * 12 + wci];
            wp0[0] = wa.x; wp0[192] = wa.y; wp0[384] = wa.z; wp0[576] = wa.w;
        }
        __syncthreads();                            // ONE barrier per tile
    }

    // store panel partial into rec[17+p] scratch region
    float* part = out + (size_t)B * NO + ((size_t)(17 + p) * B) * NJ;
    #pragma unroll
    for (int rr = 0; rr < 4; ++rr) {
        float* pp = part + (size_t)(r0 + ty * 4 + rr) * NJ + tx * 8;
        f32x4 a = {acc[rr][0], acc[rr][1], acc[rr][2], acc[rr][3]};
        f32x4 b = {acc[rr][4], acc[rr][5], acc[rr][6], acc[rr][7]};
        __builtin_nontemporal_store(a, (f32x4*)pp);
        __builtin_nontemporal_store(b, (f32x4*)(pp + 4));
    }
}

// ---------------- K2: combine + LIF + layer2 (rows 32, 256 thr) -----------
constexpr int BR2 = 32;

__global__ __launch_bounds__(256, 4) void snn_dyn(
    const float* __restrict__ b1,
    const float* __restrict__ W2,
    const float* __restrict__ b2,
    float* __restrict__ out,
    int B)
{
    __shared__ alignas(16) float4 w2s[NJ][3];       // [j][og]: W2[og*4+c][j]*2^-(j&31)
    __shared__ unsigned smaskW[2][BR2][5];          // parity row masks (4 words + pad)
    __shared__ float b2s[12];

    const int t  = threadIdx.x;
    const int tx = t & 15;                          // j = tx*8+jj
    const int ty = t >> 4;                          // row = ty*2+rr
    const int r0 = blockIdx.x * BR2;

    // ---- one-time staging: W2 (o-transposed, scaled), b2 ----
    for (int e = t; e < NJ * 3; e += 256) {
        int og = e % 3, j = e / 3;
        float sc = __int_as_float((127 - (j & 31)) << 23);   // 2^-(j&31), exact
        float vv[4];
        #pragma unroll
        for (int c = 0; c < 4; ++c) {
            int o = og * 4 + c;
            vv[c] = (o < NO) ? W2[o * NJ + j] * sc : 0.0f;
        }
        float4 v; v.x = vv[0]; v.y = vv[1]; v.z = vv[2]; v.w = vv[3];
        w2s[j][og] = v;
    }
    if (t < 12) b2s[t] = (t < NO) ? b2[t] : 0.0f;

    // ---- combine partials: cur = ((P1+P2)+P3)+b1 (reads rec[17..19]) ----
    const float* part = out + (size_t)B * NO + ((size_t)17 * B) * NJ;
    float cur[2][8];
    {
        const float* b1p = b1 + tx * 8;
        float4 ba = *(const float4*)b1p, bb = *(const float4*)(b1p + 4);
        float bf[8] = {ba.x, ba.y, ba.z, ba.w, bb.x, bb.y, bb.z, bb.w};
        #pragma unroll
        for (int rr = 0; rr < 2; ++rr) {
            const float* pp = part + (size_t)(r0 + ty * 2 + rr) * NJ + tx * 8;
            const size_t ps = (size_t)B * NJ;       // panel stride
            float4 a0 = *(const float4*)(pp);          float4 a1 = *(const float4*)(pp + 4);
            float4 c0 = *(const float4*)(pp + ps);     float4 c1 = *(const float4*)(pp + ps + 4);
            float4 d0 = *(const float4*)(pp + 2 * ps); float4 d1 = *(const float4*)(pp + 2 * ps + 4);
            float p1[8] = {a0.x, a0.y, a0.z, a0.w, a1.x, a1.y, a1.z, a1.w};
            float p2[8] = {c0.x, c0.y, c0.z, c0.w, c1.x, c1.y, c1.z, c1.w};
            float p3[8] = {d0.x, d0.y, d0.z, d0.w, d1.x, d1.y, d1.z, d1.w};
            #pragma unroll
            for (int jj = 0; jj < 8; ++jj)
                cur[rr][jj] = ((p1[jj] + p2[jj]) + p3[jj]) + bf[jj];
        }
    }
    __syncthreads();                                // w2s/b2s ready

    // ---- LIF dynamics ----
    float mem1[2][8];
    #pragma unroll
    for (int rr = 0; rr < 2; ++rr)
        #pragma unroll
        for (int jj = 0; jj < 8; ++jj) mem1[rr][jj] = 0.0f;

    const int row_l2 = t & 31;                      // layer-2: row
    const int og     = t >> 5;                      // o-group; og<3 active
    float m2[4]  = {0.f, 0.f, 0.f, 0.f};
    float cnt[4] = {0.f, 0.f, 0.f, 0.f};
    float* rec = out + (size_t)B * NO;

    #pragma unroll 1
    for (int st = 0; st < TSTEPS; ++st) {
        const int pb = st & 1;
        #pragma unroll
        for (int rr = 0; rr < 2; ++rr) {
            unsigned bt = 0;
            #pragma unroll
            for (int jj = 0; jj < 8; ++jj) {
                float m = fmaf(mem1[rr][jj], 0.25f, cur[rr][jj]);  // *0.25 exact
                float v = m - 1.0f;
                bool  s = v > 0.0f;
                mem1[rr][jj] = s ? 0.0f : m;
                bt |= s ? (1u << jj) : 0u;
            }
            ((unsigned char*)&smaskW[pb][ty * 2 + rr][0])[tx] = (unsigned char)bt;
        }
        __syncthreads();

        // dense spike store pass: wave-instruction writes contiguous 1 KB.
        // Values rebuilt from bits are exactly 1.0f/0.0f == LIF's spike.
        {
            const size_t slab = ((size_t)st * B + (size_t)r0) * NJ;
            #pragma unroll
            for (int i = 0; i < 4; ++i) {
                int c   = i * 256 + t;              // chunk of 4 floats
                int row = c >> 5;
                int wi  = (c & 31) >> 3;
                int sh  = (c & 7) * 4;
                unsigned bits = smaskW[pb][row][wi] >> sh;
                f32x4 v = { (bits & 1u) ? 1.0f : 0.0f,
                            (bits & 2u) ? 1.0f : 0.0f,
                            (bits & 4u) ? 1.0f : 0.0f,
                            (bits & 8u) ? 1.0f : 0.0f };
                __builtin_nontemporal_store(v, (f32x4*)&rec[slab + (size_t)c * 4]);
            }
        }

        if (og < 3) {
            unsigned mw[4];
            #pragma unroll
            for (int w = 0; w < 4; ++w) mw[w] = smaskW[pb][row_l2][w];
            float mm[4] = {0.f, 0.f, 0.f, 0.f};
            #pragma unroll
            for (int w = 0; w < 4; ++w) {
                unsigned bits = mw[w];
                #pragma unroll
                for (int b = 0; b < 32; ++b) {      // strict ascending j
                    float f = (float)(bits & (1u << b));      // 0 or 2^b, exact
                    float4 wv = w2s[w * 32 + b][og];          // W2 * 2^-b
                    mm[0] = fmaf(f, wv.x, mm[0]);
                    mm[1] = fmaf(f, wv.y, mm[1]);
                    mm[2] = fmaf(f, wv.z, mm[2]);
                    mm[3] = fmaf(f, wv.w, mm[3]);
                }
            }
            #pragma unroll
            for (int c = 0; c < 4; ++c) {
                float cur2 = mm[c] + b2s[og * 4 + c];   // np: chain + b2
                float nm   = fmaf(m2[c], 0.25f, cur2);  // then decay add (exact mul)
                float v2   = nm - 1.0f;
                bool  s2   = v2 > 0.0f;
                cnt[c] += s2 ? 1.0f : 0.0f;
                m2[c]  = s2 ? 0.0f : nm;
            }
        }
    }

    if (og < 3) {
        #pragma unroll
        for (int c = 0; c < 4; ++c) {
            int o = og * 4 + c;
            if (o < NO) out[(size_t)(r0 + row_l2) * NO + o] = cnt[c];
        }
    }
}

extern "C" void kernel_launch(void* const* d_in, const int* in_sizes, int n_in,
                              void* d_out, int out_size, void* d_ws, size_t ws_size,
                              hipStream_t stream)
{
    const float* x  = (const float*)d_in[0];
    const float* W1 = (const float*)d_in[1];
    const float* b1 = (const float*)d_in[2];
    const float* W2 = (const float*)d_in[3];
    const float* b2 = (const float*)d_in[4];
    float* out = (float*)d_out;
    const int B = in_sizes[0] / KDIM;       // 32768
    snn_gemm<<<3 * (B / BR1), 256, 0, stream>>>(x, W1, out, B);
    snn_dyn<<<B / BR2, 256, 0, stream>>>(b1, W2, b2, out, B);
}

// Round 3
// 1580.902 us; speedup vs baseline: 1.0656x; 1.0656x over previous
//
#include <hip/hip_runtime.h>
#include <cstddef>

// Bit-exact OpenBLAS-skylakex (KC=320) fp32 SNN — r9: split-K, spill fixed.
// Chain order (verified r3/r4/r5): per (row,j) k ascending, panel folds at
// k=320/640 realized as 3 INDEPENDENT panel GEMMs (P1,P2,P3) combined as
// ((P1+P2)+P3)+b1 — identical association, bit-exact by construction.
// LIF literal order; layer2 cur2=mm+b2 then m2*0.25+cur2, j ascending.
//
// r9 (from r8 post-mortem):
//  - r8's K1 had __launch_bounds__(256,6) -> VGPR cap ~85, allocator spilled
//    acc[4][8] to scratch (VGPR_Count=40 is impossible for 32 live accs):
//    FETCH 2.0 GB / WRITE 3.7 GB of scratch traffic, VALUBusy 3.8%.
//    Fix: (256,4) -> cap 128 >> ~75 needed. 4 blocks/CU = 16 waves/CU.
//  - K1 staging switched to the r6-proven BK=16 layout (320=20x16, 144=9x16):
//    half the barriers of r8's BK=8.
//  - K2 (snn_dyn) is r8-VERBATIM: it measured ~112 us, healthy.
//  - Partials live in rec[17..19] of `out`; each K2 block reads only its own
//    rows before its st-loop overwrites them.

typedef float f32x4 __attribute__((ext_vector_type(4)));

constexpr int KDIM   = 784;
constexpr int NJ     = 128;
constexpr int NO     = 10;
constexpr int TSTEPS = 20;

// ---------------- K1: panel GEMM (rows 64, 256 thr, 4x8 tile, BK=16) ------
constexpr int BR1 = 64;
constexpr int BK1 = 16;    // 320 = 20*16, 144 = 9*16

__global__ __launch_bounds__(256, 4) void snn_gemm(
    const float* __restrict__ x,
    const float* __restrict__ W1,
    float* __restrict__ out,
    int B)
{
    __shared__ alignas(16) float xs[2][BK1][68];    // [buf][kk][row(64)+pad]
    __shared__ alignas(16) float ws[2][BK1][192];   // [buf][kk][16 chunks*12]

    const int bid  = blockIdx.x;
    const int p    = bid % 3;                       // panel
    const int rb   = bid / 3;
    const int kbeg = p * 320;
    const int nt   = (p < 2) ? 20 : 9;              // 320/16, 144/16
    const int t    = threadIdx.x;
    const int tx   = t & 15;                        // j = tx*8+jj
    const int ty   = t >> 4;                        // row = ty*4+rr
    const int r0   = rb * BR1;

    float acc[4][8];
    #pragma unroll
    for (int rr = 0; rr < 4; ++rr)
        #pragma unroll
        for (int jj = 0; jj < 8; ++jj) acc[rr][jj] = 0.0f;

    const int xrow = t >> 2, xkf = (t & 3) * 4;     // x: row, 4-k chunk (r6)
    const int wjr  = t >> 1, wkf = (t & 1) * 8;     // W1: j, 8-k chunk (r6)
    const int wco  = wjr >> 3, wci = wjr & 7;       // chunk / intra
    const float* xrp = x  + (size_t)(r0 + xrow) * KDIM + kbeg + xkf;
    const float* wrp = W1 + (size_t)wjr * KDIM + kbeg + wkf;

    // preload tile 0 -> regs -> buf 0
    float4 xv = *(const float4*)(xrp);
    float4 wa = *(const float4*)(wrp);
    float4 wb = *(const float4*)(wrp + 4);
    {
        xs[0][xkf + 0][xrow] = xv.x; xs[0][xkf + 1][xrow] = xv.y;
        xs[0][xkf + 2][xrow] = xv.z; xs[0][xkf + 3][xrow] = xv.w;
        float* wp0 = &ws[0][wkf][wco * 12 + wci];   // k rows stride 192
        wp0[0]    = wa.x; wp0[192]  = wa.y; wp0[384]  = wa.z; wp0[576]  = wa.w;
        wp0[768]  = wb.x; wp0[960]  = wb.y; wp0[1152] = wb.z; wp0[1344] = wb.w;
    }
    __syncthreads();

    #pragma unroll 1
    for (int tt = 0; tt < nt; ++tt) {
        const int cb = tt & 1;
        if (tt < nt - 1) {                          // prefetch next tile -> regs
            const int k0n = (tt + 1) * BK1;
            xv = *(const float4*)(xrp + k0n);
            wa = *(const float4*)(wrp + k0n);
            wb = *(const float4*)(wrp + k0n + 4);
        }
        #pragma unroll
        for (int kk = 0; kk < BK1; ++kk) {          // strict ascending k
            float4 xr  = *(const float4*)&xs[cb][kk][ty * 4];
            float4 wva = *(const float4*)&ws[cb][kk][tx * 12];
            float4 wvb = *(const float4*)&ws[cb][kk][tx * 12 + 4];
            float xf[4] = {xr.x, xr.y, xr.z, xr.w};
            float wf[8] = {wva.x, wva.y, wva.z, wva.w, wvb.x, wvb.y, wvb.z, wvb.w};
            #pragma unroll
            for (int rr = 0; rr < 4; ++rr)
                #pragma unroll
                for (int jj = 0; jj < 8; ++jj)
                    acc[rr][jj] = fmaf(xf[rr], wf[jj], acc[rr][jj]);
        }
        if (tt < nt - 1) {                          // store prefetched tile
            const int nb = cb ^ 1;
            xs[nb][xkf + 0][xrow] = xv.x; xs[nb][xkf + 1][xrow] = xv.y;
            xs[nb][xkf + 2][xrow] = xv.z; xs[nb][xkf + 3][xrow] = xv.w;
            float* wp0 = &ws[nb][wkf][wco * 12 + wci];
            wp0[0]    = wa.x; wp0[192]  = wa.y; wp0[384]  = wa.z; wp0[576]  = wa.w;
            wp0[768]  = wb.x; wp0[960]  = wb.y; wp0[1152] = wb.z; wp0[1344] = wb.w;
        }
        __syncthreads();                            // ONE barrier per tile
    }

    // store panel partial into rec[17+p] scratch region (r6 rec-store shape)
    float* part = out + (size_t)B * NO + ((size_t)(17 + p) * B) * NJ;
    #pragma unroll
    for (int rr = 0; rr < 4; ++rr) {
        float* pp = part + (size_t)(r0 + ty * 4 + rr) * NJ + tx * 8;
        f32x4 a = {acc[rr][0], acc[rr][1], acc[rr][2], acc[rr][3]};
        f32x4 b = {acc[rr][4], acc[rr][5], acc[rr][6], acc[rr][7]};
        __builtin_nontemporal_store(a, (f32x4*)pp);
        __builtin_nontemporal_store(b, (f32x4*)(pp + 4));
    }
}

// ---------------- K2: combine + LIF + layer2 (r8 VERBATIM) ----------------
constexpr int BR2 = 32;

__global__ __launch_bounds__(256, 4) void snn_dyn(
    const float* __restrict__ b1,
    const float* __restrict__ W2,
    const float* __restrict__ b2,
    float* __restrict__ out,
    int B)
{
    __shared__ alignas(16) float4 w2s[NJ][3];       // [j][og]: W2[og*4+c][j]*2^-(j&31)
    __shared__ unsigned smaskW[2][BR2][5];          // parity row masks (4 words + pad)
    __shared__ float b2s[12];

    const int t  = threadIdx.x;
    const int tx = t & 15;                          // j = tx*8+jj
    const int ty = t >> 4;                          // row = ty*2+rr
    const int r0 = blockIdx.x * BR2;

    // ---- one-time staging: W2 (o-transposed, scaled), b2 ----
    for (int e = t; e < NJ * 3; e += 256) {
        int og = e % 3, j = e / 3;
        float sc = __int_as_float((127 - (j & 31)) << 23);   // 2^-(j&31), exact
        float vv[4];
        #pragma unroll
        for (int c = 0; c < 4; ++c) {
            int o = og * 4 + c;
            vv[c] = (o < NO) ? W2[o * NJ + j] * sc : 0.0f;
        }
        float4 v; v.x = vv[0]; v.y = vv[1]; v.z = vv[2]; v.w = vv[3];
        w2s[j][og] = v;
    }
    if (t < 12) b2s[t] = (t < NO) ? b2[t] : 0.0f;

    // ---- combine partials: cur = ((P1+P2)+P3)+b1 (reads rec[17..19]) ----
    const float* part = out + (size_t)B * NO + ((size_t)17 * B) * NJ;
    float cur[2][8];
    {
        const float* b1p = b1 + tx * 8;
        float4 ba = *(const float4*)b1p, bb = *(const float4*)(b1p + 4);
        float bf[8] = {ba.x, ba.y, ba.z, ba.w, bb.x, bb.y, bb.z, bb.w};
        #pragma unroll
        for (int rr = 0; rr < 2; ++rr) {
            const float* pp = part + (size_t)(r0 + ty * 2 + rr) * NJ + tx * 8;
            const size_t ps = (size_t)B * NJ;       // panel stride
            float4 a0 = *(const float4*)(pp);          float4 a1 = *(const float4*)(pp + 4);
            float4 c0 = *(const float4*)(pp + ps);     float4 c1 = *(const float4*)(pp + ps + 4);
            float4 d0 = *(const float4*)(pp + 2 * ps); float4 d1 = *(const float4*)(pp + 2 * ps + 4);
            float p1[8] = {a0.x, a0.y, a0.z, a0.w, a1.x, a1.y, a1.z, a1.w};
            float p2[8] = {c0.x, c0.y, c0.z, c0.w, c1.x, c1.y, c1.z, c1.w};
            float p3[8] = {d0.x, d0.y, d0.z, d0.w, d1.x, d1.y, d1.z, d1.w};
            #pragma unroll
            for (int jj = 0; jj < 8; ++jj)
                cur[rr][jj] = ((p1[jj] + p2[jj]) + p3[jj]) + bf[jj];
        }
    }
    __syncthreads();                                // w2s/b2s ready

    // ---- LIF dynamics ----
    float mem1[2][8];
    #pragma unroll
    for (int rr = 0; rr < 2; ++rr)
        #pragma unroll
        for (int jj = 0; jj < 8; ++jj) mem1[rr][jj] = 0.0f;

    const int row_l2 = t & 31;                      // layer-2: row
    const int og     = t >> 5;                      // o-group; og<3 active
    float m2[4]  = {0.f, 0.f, 0.f, 0.f};
    float cnt[4] = {0.f, 0.f, 0.f, 0.f};
    float* rec = out + (size_t)B * NO;

    #pragma unroll 1
    for (int st = 0; st < TSTEPS; ++st) {
        const int pb = st & 1;
        #pragma unroll
        for (int rr = 0; rr < 2; ++rr) {
            unsigned bt = 0;
            #pragma unroll
            for (int jj = 0; jj < 8; ++jj) {
                float m = fmaf(mem1[rr][jj], 0.25f, cur[rr][jj]);  // *0.25 exact
                float v = m - 1.0f;
                bool  s = v > 0.0f;
                mem1[rr][jj] = s ? 0.0f : m;
                bt |= s ? (1u << jj) : 0u;
            }
            ((unsigned char*)&smaskW[pb][ty * 2 + rr][0])[tx] = (unsigned char)bt;
        }
        __syncthreads();

        // dense spike store pass: wave-instruction writes contiguous 1 KB.
        // Values rebuilt from bits are exactly 1.0f/0.0f == LIF's spike.
        {
            const size_t slab = ((size_t)st * B + (size_t)r0) * NJ;
            #pragma unroll
            for (int i = 0; i < 4; ++i) {
                int c   = i * 256 + t;              // chunk of 4 floats
                int row = c >> 5;
                int wi  = (c & 31) >> 3;
                int sh  = (c & 7) * 4;
                unsigned bits = smaskW[pb][row][wi] >> sh;
                f32x4 v = { (bits & 1u) ? 1.0f : 0.0f,
                            (bits & 2u) ? 1.0f : 0.0f,
                            (bits & 4u) ? 1.0f : 0.0f,
                            (bits & 8u) ? 1.0f : 0.0f };
                __builtin_nontemporal_store(v, (f32x4*)&rec[slab + (size_t)c * 4]);
            }
        }

        if (og < 3) {
            unsigned mw[4];
            #pragma unroll
            for (int w = 0; w < 4; ++w) mw[w] = smaskW[pb][row_l2][w];
            float mm[4] = {0.f, 0.f, 0.f, 0.f};
            #pragma unroll
            for (int w = 0; w < 4; ++w) {
                unsigned bits = mw[w];
                #pragma unroll
                for (int b = 0; b < 32; ++b) {      // strict ascending j
                    float f = (float)(bits & (1u << b));      // 0 or 2^b, exact
                    float4 wv = w2s[w * 32 + b][og];          // W2 * 2^-b
                    mm[0] = fmaf(f, wv.x, mm[0]);
                    mm[1] = fmaf(f, wv.y, mm[1]);
                    mm[2] = fmaf(f, wv.z, mm[2]);
                    mm[3] = fmaf(f, wv.w, mm[3]);
                }
            }
            #pragma unroll
            for (int c = 0; c < 4; ++c) {
                float cur2 = mm[c] + b2s[og * 4 + c];   // np: chain + b2
                float nm   = fmaf(m2[c], 0.25f, cur2);  // then decay add (exact mul)
                float v2   = nm - 1.0f;
                bool  s2   = v2 > 0.0f;
                cnt[c] += s2 ? 1.0f : 0.0f;
                m2[c]  = s2 ? 0.0f : nm;
            }
        }
    }

    if (og < 3) {
        #pragma unroll
        for (int c = 0; c < 4; ++c) {
            int o = og * 4 + c;
            if (o < NO) out[(size_t)(r0 + row_l2) * NO + o] = cnt[c];
        }
    }
}

extern "C" void kernel_launch(void* const* d_in, const int* in_sizes, int n_in,
                              void* d_out, int out_size, void* d_ws, size_t ws_size,
                              hipStream_t stream)
{
    const float* x  = (const float*)d_in[0];
    const float* W1 = (const float*)d_in[1];
    const float* b1 = (const float*)d_in[2];
    const float* W2 = (const float*)d_in[3];
    const float* b2 = (const float*)d_in[4];
    float* out = (float*)d_out;
    const int B = in_sizes[0] / KDIM;       // 32768
    snn_gemm<<<3 * (B / BR1), 256, 0, stream>>>(x, W1, out, B);
    snn_dyn<<<B / BR2, 256, 0, stream>>>(b1, W2, b2, out, B);
}

// Round 4
// 525.134 us; speedup vs baseline: 3.2080x; 3.0105x over previous
//
#include <hip/hip_runtime.h>
#include <cstddef>

// Bit-exact OpenBLAS-skylakex (KC=320) fp32 SNN — r10: split-K, cap fixed.
// Chain order (verified r3/r4/r5): per (row,j) k ascending, panel folds at
// k=320/640 realized as 3 INDEPENDENT panel GEMMs (P1,P2,P3) combined as
// ((P1+P2)+P3)+b1 — identical association, bit-exact by construction.
// LIF literal order; layer2 cur2=mm+b2 then m2*0.25+cur2, j ascending.
//
// r10 (from r9 post-mortem):
//  - EMPIRICAL LAW (r6/r7/r8/r9 VGPR_Count data): hipcc's effective VGPR cap
//    from __launch_bounds__(256, w) is 256/w, NOT 512/w:
//      (256,2)->108 used, (256,4)->64, (256,6)->40.
//    r8/r9's K1 "spill" was the bound itself: (256,4) caps at 64 < ~85 live.
//  - Fix: BOTH kernels at (256,2) -> cap 128. Occupancy is set by ACTUAL
//    usage: K1 ~VGPR<=128 (4 waves/SIMD) + LDS 33.3KB (4 blocks/CU)
//    -> 16 waves/CU, same occupancy r9 wanted, without the spill.
//  - Bodies are r9-VERBATIM (K2 = r8-verbatim). Partials in rec[17..19].

typedef float f32x4 __attribute__((ext_vector_type(4)));

constexpr int KDIM   = 784;
constexpr int NJ     = 128;
constexpr int NO     = 10;
constexpr int TSTEPS = 20;

// ---------------- K1: panel GEMM (rows 64, 256 thr, 4x8 tile, BK=16) ------
constexpr int BR1 = 64;
constexpr int BK1 = 16;    // 320 = 20*16, 144 = 9*16

__global__ __launch_bounds__(256, 2) void snn_gemm(
    const float* __restrict__ x,
    const float* __restrict__ W1,
    float* __restrict__ out,
    int B)
{
    __shared__ alignas(16) float xs[2][BK1][68];    // [buf][kk][row(64)+pad]
    __shared__ alignas(16) float ws[2][BK1][192];   // [buf][kk][16 chunks*12]

    const int bid  = blockIdx.x;
    const int p    = bid % 3;                       // panel
    const int rb   = bid / 3;
    const int kbeg = p * 320;
    const int nt   = (p < 2) ? 20 : 9;              // 320/16, 144/16
    const int t    = threadIdx.x;
    const int tx   = t & 15;                        // j = tx*8+jj
    const int ty   = t >> 4;                        // row = ty*4+rr
    const int r0   = rb * BR1;

    float acc[4][8];
    #pragma unroll
    for (int rr = 0; rr < 4; ++rr)
        #pragma unroll
        for (int jj = 0; jj < 8; ++jj) acc[rr][jj] = 0.0f;

    const int xrow = t >> 2, xkf = (t & 3) * 4;     // x: row, 4-k chunk (r6)
    const int wjr  = t >> 1, wkf = (t & 1) * 8;     // W1: j, 8-k chunk (r6)
    const int wco  = wjr >> 3, wci = wjr & 7;       // chunk / intra
    const float* xrp = x  + (size_t)(r0 + xrow) * KDIM + kbeg + xkf;
    const float* wrp = W1 + (size_t)wjr * KDIM + kbeg + wkf;

    // preload tile 0 -> regs -> buf 0
    float4 xv = *(const float4*)(xrp);
    float4 wa = *(const float4*)(wrp);
    float4 wb = *(const float4*)(wrp + 4);
    {
        xs[0][xkf + 0][xrow] = xv.x; xs[0][xkf + 1][xrow] = xv.y;
        xs[0][xkf + 2][xrow] = xv.z; xs[0][xkf + 3][xrow] = xv.w;
        float* wp0 = &ws[0][wkf][wco * 12 + wci];   // k rows stride 192
        wp0[0]    = wa.x; wp0[192]  = wa.y; wp0[384]  = wa.z; wp0[576]  = wa.w;
        wp0[768]  = wb.x; wp0[960]  = wb.y; wp0[1152] = wb.z; wp0[1344] = wb.w;
    }
    __syncthreads();

    #pragma unroll 1
    for (int tt = 0; tt < nt; ++tt) {
        const int cb = tt & 1;
        if (tt < nt - 1) {                          // prefetch next tile -> regs
            const int k0n = (tt + 1) * BK1;
            xv = *(const float4*)(xrp + k0n);
            wa = *(const float4*)(wrp + k0n);
            wb = *(const float4*)(wrp + k0n + 4);
        }
        #pragma unroll
        for (int kk = 0; kk < BK1; ++kk) {          // strict ascending k
            float4 xr  = *(const float4*)&xs[cb][kk][ty * 4];
            float4 wva = *(const float4*)&ws[cb][kk][tx * 12];
            float4 wvb = *(const float4*)&ws[cb][kk][tx * 12 + 4];
            float xf[4] = {xr.x, xr.y, xr.z, xr.w};
            float wf[8] = {wva.x, wva.y, wva.z, wva.w, wvb.x, wvb.y, wvb.z, wvb.w};
            #pragma unroll
            for (int rr = 0; rr < 4; ++rr)
                #pragma unroll
                for (int jj = 0; jj < 8; ++jj)
                    acc[rr][jj] = fmaf(xf[rr], wf[jj], acc[rr][jj]);
        }
        if (tt < nt - 1) {                          // store prefetched tile
            const int nb = cb ^ 1;
            xs[nb][xkf + 0][xrow] = xv.x; xs[nb][xkf + 1][xrow] = xv.y;
            xs[nb][xkf + 2][xrow] = xv.z; xs[nb][xkf + 3][xrow] = xv.w;
            float* wp0 = &ws[nb][wkf][wco * 12 + wci];
            wp0[0]    = wa.x; wp0[192]  = wa.y; wp0[384]  = wa.z; wp0[576]  = wa.w;
            wp0[768]  = wb.x; wp0[960]  = wb.y; wp0[1152] = wb.z; wp0[1344] = wb.w;
        }
        __syncthreads();                            // ONE barrier per tile
    }

    // store panel partial into rec[17+p] scratch region (r6 rec-store shape)
    float* part = out + (size_t)B * NO + ((size_t)(17 + p) * B) * NJ;
    #pragma unroll
    for (int rr = 0; rr < 4; ++rr) {
        float* pp = part + (size_t)(r0 + ty * 4 + rr) * NJ + tx * 8;
        f32x4 a = {acc[rr][0], acc[rr][1], acc[rr][2], acc[rr][3]};
        f32x4 b = {acc[rr][4], acc[rr][5], acc[rr][6], acc[rr][7]};
        __builtin_nontemporal_store(a, (f32x4*)pp);
        __builtin_nontemporal_store(b, (f32x4*)(pp + 4));
    }
}

// ---------------- K2: combine + LIF + layer2 (r8 body, cap 128) -----------
constexpr int BR2 = 32;

__global__ __launch_bounds__(256, 2) void snn_dyn(
    const float* __restrict__ b1,
    const float* __restrict__ W2,
    const float* __restrict__ b2,
    float* __restrict__ out,
    int B)
{
    __shared__ alignas(16) float4 w2s[NJ][3];       // [j][og]: W2[og*4+c][j]*2^-(j&31)
    __shared__ unsigned smaskW[2][BR2][5];          // parity row masks (4 words + pad)
    __shared__ float b2s[12];

    const int t  = threadIdx.x;
    const int tx = t & 15;                          // j = tx*8+jj
    const int ty = t >> 4;                          // row = ty*2+rr
    const int r0 = blockIdx.x * BR2;

    // ---- one-time staging: W2 (o-transposed, scaled), b2 ----
    for (int e = t; e < NJ * 3; e += 256) {
        int og = e % 3, j = e / 3;
        float sc = __int_as_float((127 - (j & 31)) << 23);   // 2^-(j&31), exact
        float vv[4];
        #pragma unroll
        for (int c = 0; c < 4; ++c) {
            int o = og * 4 + c;
            vv[c] = (o < NO) ? W2[o * NJ + j] * sc : 0.0f;
        }
        float4 v; v.x = vv[0]; v.y = vv[1]; v.z = vv[2]; v.w = vv[3];
        w2s[j][og] = v;
    }
    if (t < 12) b2s[t] = (t < NO) ? b2[t] : 0.0f;

    // ---- combine partials: cur = ((P1+P2)+P3)+b1 (reads rec[17..19]) ----
    const float* part = out + (size_t)B * NO + ((size_t)17 * B) * NJ;
    float cur[2][8];
    {
        const float* b1p = b1 + tx * 8;
        float4 ba = *(const float4*)b1p, bb = *(const float4*)(b1p + 4);
        float bf[8] = {ba.x, ba.y, ba.z, ba.w, bb.x, bb.y, bb.z, bb.w};
        #pragma unroll
        for (int rr = 0; rr < 2; ++rr) {
            const float* pp = part + (size_t)(r0 + ty * 2 + rr) * NJ + tx * 8;
            const size_t ps = (size_t)B * NJ;       // panel stride
            float4 a0 = *(const float4*)(pp);          float4 a1 = *(const float4*)(pp + 4);
            float4 c0 = *(const float4*)(pp + ps);     float4 c1 = *(const float4*)(pp + ps + 4);
            float4 d0 = *(const float4*)(pp + 2 * ps); float4 d1 = *(const float4*)(pp + 2 * ps + 4);
            float p1[8] = {a0.x, a0.y, a0.z, a0.w, a1.x, a1.y, a1.z, a1.w};
            float p2[8] = {c0.x, c0.y, c0.z, c0.w, c1.x, c1.y, c1.z, c1.w};
            float p3[8] = {d0.x, d0.y, d0.z, d0.w, d1.x, d1.y, d1.z, d1.w};
            #pragma unroll
            for (int jj = 0; jj < 8; ++jj)
                cur[rr][jj] = ((p1[jj] + p2[jj]) + p3[jj]) + bf[jj];
        }
    }
    __syncthreads();                                // w2s/b2s ready

    // ---- LIF dynamics ----
    float mem1[2][8];
    #pragma unroll
    for (int rr = 0; rr < 2; ++rr)
        #pragma unroll
        for (int jj = 0; jj < 8; ++jj) mem1[rr][jj] = 0.0f;

    const int row_l2 = t & 31;                      // layer-2: row
    const int og     = t >> 5;                      // o-group; og<3 active
    float m2[4]  = {0.f, 0.f, 0.f, 0.f};
    float cnt[4] = {0.f, 0.f, 0.f, 0.f};
    float* rec = out + (size_t)B * NO;

    #pragma unroll 1
    for (int st = 0; st < TSTEPS; ++st) {
        const int pb = st & 1;
        #pragma unroll
        for (int rr = 0; rr < 2; ++rr) {
            unsigned bt = 0;
            #pragma unroll
            for (int jj = 0; jj < 8; ++jj) {
                float m = fmaf(mem1[rr][jj], 0.25f, cur[rr][jj]);  // *0.25 exact
                float v = m - 1.0f;
                bool  s = v > 0.0f;
                mem1[rr][jj] = s ? 0.0f : m;
                bt |= s ? (1u << jj) : 0u;
            }
            ((unsigned char*)&smaskW[pb][ty * 2 + rr][0])[tx] = (unsigned char)bt;
        }
        __syncthreads();

        // dense spike store pass: wave-instruction writes contiguous 1 KB.
        // Values rebuilt from bits are exactly 1.0f/0.0f == LIF's spike.
        {
            const size_t slab = ((size_t)st * B + (size_t)r0) * NJ;
            #pragma unroll
            for (int i = 0; i < 4; ++i) {
                int c   = i * 256 + t;              // chunk of 4 floats
                int row = c >> 5;
                int wi  = (c & 31) >> 3;
                int sh  = (c & 7) * 4;
                unsigned bits = smaskW[pb][row][wi] >> sh;
                f32x4 v = { (bits & 1u) ? 1.0f : 0.0f,
                            (bits & 2u) ? 1.0f : 0.0f,
                            (bits & 4u) ? 1.0f : 0.0f,
                            (bits & 8u) ? 1.0f : 0.0f };
                __builtin_nontemporal_store(v, (f32x4*)&rec[slab + (size_t)c * 4]);
            }
        }

        if (og < 3) {
            unsigned mw[4];
            #pragma unroll
            for (int w = 0; w < 4; ++w) mw[w] = smaskW[pb][row_l2][w];
            float mm[4] = {0.f, 0.f, 0.f, 0.f};
            #pragma unroll
            for (int w = 0; w < 4; ++w) {
                unsigned bits = mw[w];
                #pragma unroll
                for (int b = 0; b < 32; ++b) {      // strict ascending j
                    float f = (float)(bits & (1u << b));      // 0 or 2^b, exact
                    float4 wv = w2s[w * 32 + b][og];          // W2 * 2^-b
                    mm[0] = fmaf(f, wv.x, mm[0]);
                    mm[1] = fmaf(f, wv.y, mm[1]);
                    mm[2] = fmaf(f, wv.z, mm[2]);
                    mm[3] = fmaf(f, wv.w, mm[3]);
                }
            }
            #pragma unroll
            for (int c = 0; c < 4; ++c) {
                float cur2 = mm[c] + b2s[og * 4 + c];   // np: chain + b2
                float nm   = fmaf(m2[c], 0.25f, cur2);  // then decay add (exact mul)
                float v2   = nm - 1.0f;
                bool  s2   = v2 > 0.0f;
                cnt[c] += s2 ? 1.0f : 0.0f;
                m2[c]  = s2 ? 0.0f : nm;
            }
        }
    }

    if (og < 3) {
        #pragma unroll
        for (int c = 0; c < 4; ++c) {
            int o = og * 4 + c;
            if (o < NO) out[(size_t)(r0 + row_l2) * NO + o] = cnt[c];
        }
    }
}

extern "C" void kernel_launch(void* const* d_in, const int* in_sizes, int n_in,
                              void* d_out, int out_size, void* d_ws, size_t ws_size,
                              hipStream_t stream)
{
    const float* x  = (const float*)d_in[0];
    const float* W1 = (const float*)d_in[1];
    const float* b1 = (const float*)d_in[2];
    const float* W2 = (const float*)d_in[3];
    const float* b2 = (const float*)d_in[4];
    float* out = (float*)d_out;
    const int B = in_sizes[0] / KDIM;       // 32768
    snn_gemm<<<3 * (B / BR1), 256, 0, stream>>>(x, W1, out, B);
    snn_dyn<<<B / BR2, 256, 0, stream>>>(b1, W2, b2, out, B);
}